// Round 1
// baseline (583.904 us; speedup 1.0000x reference)
//
#include <hip/hip_runtime.h>

#define DEV static __device__ __forceinline__

typedef short s16;
typedef __attribute__((ext_vector_type(8))) short short8;
typedef __attribute__((ext_vector_type(4))) float f32x4;

#define NB 2
#define NH 8
#define SL 2048
#define DM 512
#define DH 64
#define NTOP 7

DEV short f2bf(float x){
  union { float f; unsigned u; } v; v.f = x;
  unsigned r = v.u + 0x7fffu + ((v.u >> 16) & 1u);
  return (short)(r >> 16);
}
DEV float bf2f(short b){
  union { float f; unsigned u; } v; v.u = ((unsigned)(unsigned short)b) << 16;
  return v.f;
}
DEV f32x4 mfma16(short8 a, short8 b, f32x4 c){
  return __builtin_amdgcn_mfma_f32_16x16x32_bf16(a, b, c, 0, 0, 0);
}

// ---------- converts ----------
__global__ void cvt_kernel(const float* __restrict__ x, s16* __restrict__ y, int n){
  int i = blockIdx.x * 256 + threadIdx.x;
  if (i < n) y[i] = f2bf(x[i]);
}
__global__ void cvt_split_kernel(const float* __restrict__ x, s16* __restrict__ hi,
                                 s16* __restrict__ lo, int n){
  int i = blockIdx.x * 256 + threadIdx.x;
  if (i < n){
    float v = x[i];
    short h = f2bf(v);
    hi[i] = h;
    lo[i] = f2bf(v - bf2f(h));
  }
}

// khatT[b][h][k][d] = key[b, d*32 + k/64, h*64 + k%64]   (split hi/lo)
__global__ void khatT_kernel(const float* __restrict__ key, s16* __restrict__ khi,
                             s16* __restrict__ klo){
  int idx = blockIdx.x * 256 + threadIdx.x;
  int d = idx & 63;
  int k = (idx >> 6) & (SL - 1);
  int h = (idx >> 17) & 7;
  int b = idx >> 20;
  float v = key[((size_t)b*SL + d*32 + (k >> 6))*DM + h*DH + (k & 63)];
  short hh = f2bf(v);
  khi[idx] = hh;
  klo[idx] = f2bf(v - bf2f(hh));
}

// VpT[b][h][d][k] = Vp[b][k][h*64+d]
__global__ void vpt_kernel(const s16* __restrict__ Vp, s16* __restrict__ VpT){
  int idx = blockIdx.x * 256 + threadIdx.x;
  int c = idx & 511;
  int k = (idx >> 9) & (SL - 1);
  int b = idx >> 20;
  int h = c >> 6, d = c & 63;
  VpT[(((size_t)b*NH + h)*DH + d)*SL + k] = Vp[idx];
}

// ---------- GEMM: C[n][o] = sum_k A[n][k]*Bw[o][k] + bias[o] ----------
template<int OUTF32>
__global__ __launch_bounds__(256) void gemm_bt(const s16* __restrict__ A, const s16* __restrict__ Bw,
        const float* __restrict__ bias, void* __restrict__ Cout, int Nrows){
  int bid = blockIdx.x;
  int nt = bid >> 3, ot = bid & 7;
  int w = threadIdx.x >> 6, l = threadIdx.x & 63;
  int lr = l & 15, lg = l >> 4;
  int n0 = nt*64 + w*16, o0 = ot*64;
  const s16* Ap = A  + (size_t)(n0 + lr)*DM + lg*8;
  const s16* Bp = Bw + (size_t)(o0 + lr)*DM + lg*8;
  f32x4 acc[4] = {};
  #pragma unroll 4
  for (int k0 = 0; k0 < DM; k0 += 32){
    short8 a = *(const short8*)(Ap + k0);
    #pragma unroll
    for (int c = 0; c < 4; ++c){
      short8 b = *(const short8*)(Bp + (size_t)c*16*DM + k0);
      acc[c] = mfma16(a, b, acc[c]);
    }
  }
  #pragma unroll
  for (int c = 0; c < 4; ++c){
    int col = o0 + c*16 + lr;
    float bb = bias[col];
    #pragma unroll
    for (int j = 0; j < 4; ++j){
      int row = n0 + lg*4 + j;
      float v = acc[c][j] + bb;
      if (OUTF32) ((float*)Cout)[(size_t)row*DM + col] = v;
      else        ((s16*) Cout)[(size_t)row*DM + col] = f2bf(v);
    }
  }
  (void)Nrows;
}

// ---------- stats: M[b,h,q] = max_k QK - mean_k QK  (split-bf16, 3 products) ----------
__global__ __launch_bounds__(256) void stats_kernel(const s16* __restrict__ qhi, const s16* __restrict__ qlo,
        const s16* __restrict__ khi, const s16* __restrict__ klo, float* __restrict__ M){
  int bid = blockIdx.x;
  int qt = bid & 31, h = (bid >> 5) & 7, b = bid >> 8;
  int w = threadIdx.x >> 6, l = threadIdx.x & 63;
  int lr = l & 15, lg = l >> 4;
  int q0 = qt*64 + w*16;
  const s16* qp = qhi + ((size_t)b*SL + q0 + lr)*DM + h*DH + lg*8;
  const s16* ql = qlo + ((size_t)b*SL + q0 + lr)*DM + h*DH + lg*8;
  short8 ah0 = *(const short8*)qp;
  short8 ah1 = *(const short8*)(qp + 32);
  short8 al0 = *(const short8*)ql;
  short8 al1 = *(const short8*)(ql + 32);
  const s16* kb = khi + ((size_t)b*NH + h)*SL*DH;
  const s16* kl = klo + ((size_t)b*NH + h)*SL*DH;
  float mx[4] = {-1e30f,-1e30f,-1e30f,-1e30f};
  float sm[4] = {0.f,0.f,0.f,0.f};
  for (int k0 = 0; k0 < SL; k0 += 32){
    #pragma unroll
    for (int ct = 0; ct < 2; ++ct){
      const s16* kp  = kb + (size_t)(k0 + ct*16 + lr)*DH + lg*8;
      const s16* kpl = kl + (size_t)(k0 + ct*16 + lr)*DH + lg*8;
      short8 bh0 = *(const short8*)kp;
      short8 bh1 = *(const short8*)(kp + 32);
      short8 bl0 = *(const short8*)kpl;
      short8 bl1 = *(const short8*)(kpl + 32);
      f32x4 s = {};
      s = mfma16(ah0, bh0, s);
      s = mfma16(ah1, bh1, s);
      s = mfma16(ah0, bl0, s);
      s = mfma16(ah1, bl1, s);
      s = mfma16(al0, bh0, s);
      s = mfma16(al1, bh1, s);
      #pragma unroll
      for (int j = 0; j < 4; ++j){
        mx[j] = fmaxf(mx[j], s[j]);
        sm[j] += s[j];
      }
    }
  }
  #pragma unroll
  for (int j = 0; j < 4; ++j){
    mx[j] = fmaxf(mx[j], __shfl_xor(mx[j], 1));
    mx[j] = fmaxf(mx[j], __shfl_xor(mx[j], 2));
    mx[j] = fmaxf(mx[j], __shfl_xor(mx[j], 4));
    mx[j] = fmaxf(mx[j], __shfl_xor(mx[j], 8));
    sm[j] += __shfl_xor(sm[j], 1);
    sm[j] += __shfl_xor(sm[j], 2);
    sm[j] += __shfl_xor(sm[j], 4);
    sm[j] += __shfl_xor(sm[j], 8);
  }
  if (lr == 0){
    #pragma unroll
    for (int j = 0; j < 4; ++j)
      M[((size_t)b*NH + h)*SL + q0 + lg*4 + j] = mx[j] - sm[j]*(1.0f/SL);
  }
}

// ---------- top-7 per (b,h), jax.lax.top_k tie semantics (lower index first) ----------
__global__ __launch_bounds__(64) void topk_kernel(const float* __restrict__ M,
        int* __restrict__ topidx, int* __restrict__ rowsel){
  int bh = blockIdx.x;
  int l = threadIdx.x;
  __shared__ float smv[SL];
  const float* Mr = M + (size_t)bh*SL;
  for (int i = l; i < SL; i += 64){
    smv[i] = Mr[i];
    rowsel[(size_t)bh*SL + i] = -1;
  }
  __syncthreads();
  for (int t = 0; t < NTOP; ++t){
    float bvv = -1e38f; int bi = SL;
    for (int i = l; i < SL; i += 64){
      float v = smv[i];
      if (v > bvv){ bvv = v; bi = i; }
    }
    for (int off = 32; off >= 1; off >>= 1){
      float ov = __shfl_xor(bvv, off);
      int oi = __shfl_xor(bi, off);
      if (ov > bvv || (ov == bvv && oi < bi)){ bvv = ov; bi = oi; }
    }
    if (l == 0){
      topidx[bh*8 + t] = bi;
      rowsel[(size_t)bh*SL + bi] = t;
    }
    smv[bi] = -1e38f;
    __syncthreads();
  }
}

// ---------- mask rows (exact f32): maskrows[b,h,t,k] = sum_d Q[b,q,h*64+d]*Kr[...] ----------
__global__ __launch_bounds__(256) void maskrow_kernel(const float* __restrict__ query,
        const float* __restrict__ key, const int* __restrict__ topidx, float* __restrict__ maskrows){
  int bid = blockIdx.x;            // B*H*NTOP
  int t = bid % NTOP;
  int bh = bid / NTOP;
  int h = bh & 7, b = bh >> 3;
  int q = topidx[bh*8 + t];
  __shared__ float qs[DH];
  if (threadIdx.x < DH) qs[threadIdx.x] = query[((size_t)b*SL + q)*DM + h*DH + threadIdx.x];
  __syncthreads();
  for (int k = threadIdx.x; k < SL; k += 256){
    const float* kp = key + ((size_t)b*SL + (k >> 6))*DM + h*DH + (k & 63);
    float acc = 0.f;
    #pragma unroll
    for (int d = 0; d < DH; ++d)
      acc = fmaf(qs[d], kp[(size_t)d*32*DM], acc);
    maskrows[((size_t)bh*NTOP + t)*SL + k] = acc;
  }
}

// ---------- flash attention with additive mask on selected rows ----------
__global__ __launch_bounds__(256) void flash_kernel(const s16* __restrict__ Qp, const s16* __restrict__ Kp,
        const s16* __restrict__ VpT, const float* __restrict__ maskrows, const int* __restrict__ rowsel,
        s16* __restrict__ outh){
  int bid = blockIdx.x;
  int qt = bid & 31, h = (bid >> 5) & 7, b = bid >> 8;
  int w = threadIdx.x >> 6, l = threadIdx.x & 63;
  int lr = l & 15, lg = l >> 4;
  int q0 = qt*64 + w*16;
  int bh = b*NH + h;
  __shared__ __align__(16) s16 pbuf[4][16][32];
  const s16* qp = Qp + ((size_t)b*SL + q0 + lr)*DM + h*DH + lg*8;
  short8 aq0 = *(const short8*)qp;
  short8 aq1 = *(const short8*)(qp + 32);
  int sel[4];
  const float* mrow[4];
  #pragma unroll
  for (int j = 0; j < 4; ++j){
    sel[j] = rowsel[(size_t)bh*SL + q0 + lg*4 + j];
    mrow[j] = maskrows + ((size_t)bh*NTOP + (sel[j] >= 0 ? sel[j] : 0))*SL;
  }
  const s16* kpb = Kp + (size_t)b*SL*DM + h*DH;
  const s16* vtb = VpT + (size_t)bh*DH*SL;
  f32x4 acc[4] = {};
  float m[4]    = {-1e30f,-1e30f,-1e30f,-1e30f};
  float lsum[4] = {0.f,0.f,0.f,0.f};
  for (int k0 = 0; k0 < SL; k0 += 32){
    const s16* kp0 = kpb + (size_t)(k0 + lr)*DM;
    short8 b00 = *(const short8*)(kp0 + lg*8);
    short8 b01 = *(const short8*)(kp0 + 32 + lg*8);
    const s16* kp1 = kp0 + (size_t)16*DM;
    short8 b10 = *(const short8*)(kp1 + lg*8);
    short8 b11 = *(const short8*)(kp1 + 32 + lg*8);
    f32x4 s0 = {}, s1 = {};
    s0 = mfma16(aq0, b00, s0);
    s0 = mfma16(aq1, b01, s0);
    s1 = mfma16(aq0, b10, s1);
    s1 = mfma16(aq1, b11, s1);
    float p0[4], p1[4], alpha[4];
    #pragma unroll
    for (int j = 0; j < 4; ++j){
      float v0 = s0[j]*0.125f, v1 = s1[j]*0.125f;
      if (sel[j] >= 0){
        v0 += mrow[j][k0 + lr];
        v1 += mrow[j][k0 + 16 + lr];
      }
      float t = fmaxf(v0, v1);
      t = fmaxf(t, __shfl_xor(t, 1));
      t = fmaxf(t, __shfl_xor(t, 2));
      t = fmaxf(t, __shfl_xor(t, 4));
      t = fmaxf(t, __shfl_xor(t, 8));
      float mnew = fmaxf(m[j], t);
      float a = expf(m[j] - mnew);
      v0 = expf(v0 - mnew);
      v1 = expf(v1 - mnew);
      float rs = v0 + v1;
      rs += __shfl_xor(rs, 1);
      rs += __shfl_xor(rs, 2);
      rs += __shfl_xor(rs, 4);
      rs += __shfl_xor(rs, 8);
      lsum[j] = lsum[j]*a + rs;
      m[j] = mnew;
      alpha[j] = a;
      p0[j] = v0; p1[j] = v1;
    }
    #pragma unroll
    for (int c = 0; c < 4; ++c)
      #pragma unroll
      for (int j = 0; j < 4; ++j)
        acc[c][j] *= alpha[j];
    #pragma unroll
    for (int j = 0; j < 4; ++j){
      pbuf[w][lg*4 + j][lr]      = f2bf(p0[j]);
      pbuf[w][lg*4 + j][16 + lr] = f2bf(p1[j]);
    }
    __syncthreads();
    short8 pa = *(const short8*)&pbuf[w][lr][lg*8];
    #pragma unroll
    for (int c = 0; c < 4; ++c){
      short8 bv = *(const short8*)(vtb + (size_t)(c*16 + lr)*SL + k0 + lg*8);
      acc[c] = mfma16(pa, bv, acc[c]);
    }
    __syncthreads();
  }
  float rinv[4];
  #pragma unroll
  for (int j = 0; j < 4; ++j) rinv[j] = 1.0f / lsum[j];
  #pragma unroll
  for (int c = 0; c < 4; ++c)
    #pragma unroll
    for (int j = 0; j < 4; ++j)
      outh[((size_t)b*SL + q0 + lg*4 + j)*DM + h*DH + c*16 + lr] = f2bf(acc[c][j]*rinv[j]);
}

extern "C" void kernel_launch(void* const* d_in, const int* in_sizes, int n_in,
                              void* d_out, int out_size, void* d_ws, size_t ws_size,
                              hipStream_t stream){
  (void)in_sizes; (void)n_in; (void)out_size;
  const float* query = (const float*)d_in[0];
  const float* key   = (const float*)d_in[1];
  const float* value = (const float*)d_in[2];
  const float* wq    = (const float*)d_in[3];
  const float* wk    = (const float*)d_in[4];
  const float* wv    = (const float*)d_in[5];
  const float* bq    = (const float*)d_in[6];
  const float* bk    = (const float*)d_in[7];
  const float* bv    = (const float*)d_in[8];
  const float* wo    = (const float*)d_in[9];
  const float* bo    = (const float*)d_in[10];

  const size_t NE = (size_t)NB*SL*DM;     // 2,097,152
  const size_t WE = (size_t)DM*DM;        // 262,144

  char* p = (char*)d_ws;
  size_t off = 0;
  auto alloc = [&](size_t n)->char*{ char* r = p + off; off += (n + 255) & ~(size_t)255; return r; };
  s16* q_hi = (s16*)alloc(NE*2);
  s16* q_lo = (s16*)alloc(NE*2);
  s16* xk   = (s16*)alloc(NE*2);
  s16* xv   = (s16*)alloc(NE*2);
  s16* khatT_hi = (s16*)alloc(NE*2);
  s16* khatT_lo = (s16*)alloc(NE*2);
  s16* wqb = (s16*)alloc(WE*2);
  s16* wkb = (s16*)alloc(WE*2);
  s16* wvb = (s16*)alloc(WE*2);
  s16* wob = (s16*)alloc(WE*2);
  s16* Qp  = (s16*)alloc(NE*2);
  s16* Kp  = (s16*)alloc(NE*2);
  s16* Vp  = (s16*)alloc(NE*2);
  s16* VpT = (s16*)alloc(NE*2);
  float* M      = (float*)alloc((size_t)NB*NH*SL*4);
  int* topidx   = (int*)alloc((size_t)NB*NH*8*4);
  int* rowsel   = (int*)alloc((size_t)NB*NH*SL*4);
  float* maskrows = (float*)alloc((size_t)NB*NH*NTOP*SL*4);
  s16* outh = (s16*)alloc(NE*2);
  if (off > ws_size) return;  // insufficient scratch -> visible failure, no OOB writes

  int nb = (int)(NE/256);
  int wb = (int)(WE/256);
  cvt_split_kernel<<<nb, 256, 0, stream>>>(query, q_hi, q_lo, (int)NE);
  cvt_kernel<<<nb, 256, 0, stream>>>(key,   xk, (int)NE);
  cvt_kernel<<<nb, 256, 0, stream>>>(value, xv, (int)NE);
  cvt_kernel<<<wb, 256, 0, stream>>>(wq, wqb, (int)WE);
  cvt_kernel<<<wb, 256, 0, stream>>>(wk, wkb, (int)WE);
  cvt_kernel<<<wb, 256, 0, stream>>>(wv, wvb, (int)WE);
  cvt_kernel<<<wb, 256, 0, stream>>>(wo, wob, (int)WE);
  khatT_kernel<<<nb, 256, 0, stream>>>(key, khatT_hi, khatT_lo);

  gemm_bt<0><<<512, 256, 0, stream>>>(q_hi, wqb, bq, Qp, NB*SL);
  gemm_bt<0><<<512, 256, 0, stream>>>(xk,   wkb, bk, Kp, NB*SL);
  gemm_bt<0><<<512, 256, 0, stream>>>(xv,   wvb, bv, Vp, NB*SL);
  vpt_kernel<<<nb, 256, 0, stream>>>(Vp, VpT);

  stats_kernel<<<NB*NH*(SL/64), 256, 0, stream>>>(q_hi, q_lo, khatT_hi, khatT_lo, M);
  topk_kernel<<<NB*NH, 64, 0, stream>>>(M, topidx, rowsel);
  maskrow_kernel<<<NB*NH*NTOP, 256, 0, stream>>>(query, key, topidx, maskrows);

  flash_kernel<<<NB*NH*(SL/64), 256, 0, stream>>>(Qp, Kp, VpT, maskrows, rowsel, outh);
  gemm_bt<1><<<512, 256, 0, stream>>>(outh, wob, bo, d_out, NB*SL);
}

// Round 2
// 540.931 us; speedup vs baseline: 1.0794x; 1.0794x over previous
//
#include <hip/hip_runtime.h>

#define DEV static __device__ __forceinline__

typedef short s16;
typedef __attribute__((ext_vector_type(4))) short short4_t;
typedef __attribute__((ext_vector_type(8))) short short8;
typedef __attribute__((ext_vector_type(4))) float f32x4;

#define NB 2
#define NH 8
#define SL 2048
#define DM 512
#define DH 64
#define NTOP 7
#define LOG2E 1.4426950408889634f

DEV short f2bf(float x){
  union { float f; unsigned u; } v; v.f = x;
  unsigned r = v.u + 0x7fffu + ((v.u >> 16) & 1u);
  return (short)(r >> 16);
}
DEV float bf2f(short b){
  union { float f; unsigned u; } v; v.u = ((unsigned)(unsigned short)b) << 16;
  return v.f;
}
DEV f32x4 mfma16(short8 a, short8 b, f32x4 c){
  return __builtin_amdgcn_mfma_f32_16x16x32_bf16(a, b, c, 0, 0, 0);
}
DEV unsigned cvtpk(float lo, float hi){
  unsigned r;
  asm("v_cvt_pk_bf16_f32 %0, %1, %2" : "=v"(r) : "v"(lo), "v"(hi));
  return r;
}

// ---------- fused prep: converts + khatT gather ----------
__global__ void prep_kernel(const float* __restrict__ query, const float* __restrict__ key,
    const float* __restrict__ value,
    const float* __restrict__ wq, const float* __restrict__ wk,
    const float* __restrict__ wv, const float* __restrict__ wo,
    s16* __restrict__ q_hi, s16* __restrict__ q_lo, s16* __restrict__ xk, s16* __restrict__ xv,
    s16* __restrict__ khi, s16* __restrict__ klo,
    s16* __restrict__ wqb, s16* __restrict__ wkb, s16* __restrict__ wvb, s16* __restrict__ wob){
  const int nbb = (NB*SL*DM)/256;   // 8192
  const int wbb = (DM*DM)/256;      // 1024
  int bid = blockIdx.x;
  int t = threadIdx.x;
  if (bid < nbb){
    int i = bid*256 + t;
    float v = query[i];
    short h = f2bf(v);
    q_hi[i] = h;
    q_lo[i] = f2bf(v - bf2f(h));
    return;
  }
  bid -= nbb;
  if (bid < nbb){ int i = bid*256 + t; xk[i] = f2bf(key[i]); return; }
  bid -= nbb;
  if (bid < nbb){ int i = bid*256 + t; xv[i] = f2bf(value[i]); return; }
  bid -= nbb;
  if (bid < nbb){
    int idx = bid*256 + t;
    int d = idx & 63;
    int k = (idx >> 6) & (SL - 1);
    int h = (idx >> 17) & 7;
    int b = idx >> 20;
    float v = key[((size_t)b*SL + d*32 + (k >> 6))*DM + h*DH + (k & 63)];
    short hh = f2bf(v);
    khi[idx] = hh;
    klo[idx] = f2bf(v - bf2f(hh));
    return;
  }
  bid -= nbb;
  if (bid < wbb){ int i = bid*256 + t; wqb[i] = f2bf(wq[i]); return; }
  bid -= wbb;
  if (bid < wbb){ int i = bid*256 + t; wkb[i] = f2bf(wk[i]); return; }
  bid -= wbb;
  if (bid < wbb){ int i = bid*256 + t; wvb[i] = f2bf(wv[i]); return; }
  bid -= wbb;
  if (bid < wbb){ int i = bid*256 + t; wob[i] = f2bf(wo[i]); return; }
}

// VpT[b][h][d][k] = Vp[b][k][h*64+d]
__global__ void vpt_kernel(const s16* __restrict__ Vp, s16* __restrict__ VpT){
  int idx = blockIdx.x * 256 + threadIdx.x;
  int c = idx & 511;
  int k = (idx >> 9) & (SL - 1);
  int b = idx >> 20;
  int h = c >> 6, d = c & 63;
  VpT[(((size_t)b*NH + h)*DH + d)*SL + k] = Vp[idx];
}

// ---------- GEMM body: C[n][o] = sum_k A[n][k]*Bw[o][k] + bias[o] ----------
template<int OUTF32>
DEV void gemm_body(const s16* __restrict__ A, const s16* __restrict__ Bw,
        const float* __restrict__ bias, void* __restrict__ Cout, int bid, int tid){
  int nt = bid >> 3, ot = bid & 7;
  int w = tid >> 6, l = tid & 63;
  int lr = l & 15, lg = l >> 4;
  int n0 = nt*64 + w*16, o0 = ot*64;
  const s16* Ap = A  + (size_t)(n0 + lr)*DM + lg*8;
  const s16* Bp = Bw + (size_t)(o0 + lr)*DM + lg*8;
  f32x4 acc[4] = {};
  #pragma unroll 4
  for (int k0 = 0; k0 < DM; k0 += 32){
    short8 a = *(const short8*)(Ap + k0);
    #pragma unroll
    for (int c = 0; c < 4; ++c){
      short8 b = *(const short8*)(Bp + (size_t)c*16*DM + k0);
      acc[c] = mfma16(a, b, acc[c]);
    }
  }
  #pragma unroll
  for (int c = 0; c < 4; ++c){
    int col = o0 + c*16 + lr;
    float bb = bias[col];
    #pragma unroll
    for (int j = 0; j < 4; ++j){
      int row = n0 + lg*4 + j;
      float v = acc[c][j] + bb;
      if (OUTF32) ((float*)Cout)[(size_t)row*DM + col] = v;
      else        ((s16*) Cout)[(size_t)row*DM + col] = f2bf(v);
    }
  }
}

// 3 projection GEMMs in one launch (blockIdx/512 selects which)
__global__ __launch_bounds__(256) void gemm_proj(const s16* __restrict__ Aq, const s16* __restrict__ Ak,
        const s16* __restrict__ Av, const s16* __restrict__ Wq, const s16* __restrict__ Wk,
        const s16* __restrict__ Wv, const float* __restrict__ bq, const float* __restrict__ bk,
        const float* __restrict__ bv, s16* __restrict__ Oq, s16* __restrict__ Ok, s16* __restrict__ Ov){
  int which = blockIdx.x >> 9;
  const s16* A  = which == 0 ? Aq : which == 1 ? Ak : Av;
  const s16* Bw = which == 0 ? Wq : which == 1 ? Wk : Wv;
  const float* bias = which == 0 ? bq : which == 1 ? bk : bv;
  s16* C = which == 0 ? Oq : which == 1 ? Ok : Ov;
  gemm_body<0>(A, Bw, bias, C, blockIdx.x & 511, threadIdx.x);
}

__global__ __launch_bounds__(256) void gemm_out(const s16* __restrict__ A, const s16* __restrict__ Bw,
        const float* __restrict__ bias, float* __restrict__ Cout){
  gemm_body<1>(A, Bw, bias, Cout, blockIdx.x, threadIdx.x);
}

// ---------- stats (swapped layout): M[b,h,q] = max_k QK - mean_k QK ----------
// S^T = mfma(Khat, Q): lane(lr,lg) reg j = QK[k=k0+t*16+lg*4+j][q=q0+lr].
// All 32 per-lane values belong to row q0+lr -> local max/sum, 2 shfls at end.
__global__ __launch_bounds__(256) void stats_kernel(const s16* __restrict__ qhi, const s16* __restrict__ qlo,
        const s16* __restrict__ khi, const s16* __restrict__ klo, float* __restrict__ M){
  int bid = blockIdx.x;
  int qt = bid & 31, h = (bid >> 5) & 7, b = bid >> 8;
  int w = threadIdx.x >> 6, l = threadIdx.x & 63;
  int lr = l & 15, lg = l >> 4;
  int q0 = qt*64 + w*16;
  const s16* qp  = qhi + ((size_t)b*SL + q0 + lr)*DM + h*DH + lg*8;
  const s16* qlp = qlo + ((size_t)b*SL + q0 + lr)*DM + h*DH + lg*8;
  short8 qh0 = *(const short8*)qp;
  short8 qh1 = *(const short8*)(qp + 32);
  short8 ql0 = *(const short8*)qlp;
  short8 ql1 = *(const short8*)(qlp + 32);
  const s16* kb  = khi + ((size_t)b*NH + h)*SL*DH;
  const s16* klb = klo + ((size_t)b*NH + h)*SL*DH;
  float mx = -1e30f, sm = 0.f;
  for (int k0 = 0; k0 < SL; k0 += 128){
    #pragma unroll
    for (int t = 0; t < 8; ++t){
      const s16* kp  = kb  + (size_t)(k0 + t*16 + lr)*DH + lg*8;
      const s16* kpl = klb + (size_t)(k0 + t*16 + lr)*DH + lg*8;
      short8 kh0 = *(const short8*)kp;
      short8 kh1 = *(const short8*)(kp + 32);
      short8 kl0 = *(const short8*)kpl;
      short8 kl1 = *(const short8*)(kpl + 32);
      f32x4 s = {};
      s = mfma16(kh0, qh0, s);
      s = mfma16(kh1, qh1, s);
      s = mfma16(kl0, qh0, s);
      s = mfma16(kl1, qh1, s);
      s = mfma16(kh0, ql0, s);
      s = mfma16(kh1, ql1, s);
      #pragma unroll
      for (int j = 0; j < 4; ++j){ mx = fmaxf(mx, s[j]); sm += s[j]; }
    }
  }
  mx = fmaxf(mx, __shfl_xor(mx, 16));
  mx = fmaxf(mx, __shfl_xor(mx, 32));
  sm += __shfl_xor(sm, 16);
  sm += __shfl_xor(sm, 32);
  if (lg == 0)
    M[((size_t)b*NH + h)*SL + q0 + lr] = mx - sm*(1.0f/SL);
}

// ---------- top-7 per (b,h), jax.lax.top_k tie semantics (lower index first) ----------
__global__ __launch_bounds__(64) void topk_kernel(const float* __restrict__ M,
        int* __restrict__ topidx, int* __restrict__ rowsel){
  int bh = blockIdx.x;
  int l = threadIdx.x;
  __shared__ float smv[SL];
  const float* Mr = M + (size_t)bh*SL;
  for (int i = l; i < SL; i += 64){
    smv[i] = Mr[i];
    rowsel[(size_t)bh*SL + i] = -1;
  }
  __syncthreads();
  for (int t = 0; t < NTOP; ++t){
    float bvv = -1e38f; int bi = SL;
    for (int i = l; i < SL; i += 64){
      float v = smv[i];
      if (v > bvv){ bvv = v; bi = i; }
    }
    for (int off = 32; off >= 1; off >>= 1){
      float ov = __shfl_xor(bvv, off);
      int oi = __shfl_xor(bi, off);
      if (ov > bvv || (ov == bvv && oi < bi)){ bvv = ov; bi = oi; }
    }
    if (l == 0){
      topidx[bh*8 + t] = bi;
      rowsel[(size_t)bh*SL + bi] = t;
    }
    smv[bi] = -1e38f;
    __syncthreads();
  }
}

// ---------- mask rows (exact f32) ----------
__global__ __launch_bounds__(256) void maskrow_kernel(const float* __restrict__ query,
        const float* __restrict__ key, const int* __restrict__ topidx, float* __restrict__ maskrows){
  int bid = blockIdx.x;            // B*H*NTOP
  int t = bid % NTOP;
  int bh = bid / NTOP;
  int h = bh & 7, b = bh >> 3;
  int q = topidx[bh*8 + t];
  __shared__ float qs[DH];
  if (threadIdx.x < DH) qs[threadIdx.x] = query[((size_t)b*SL + q)*DM + h*DH + threadIdx.x];
  __syncthreads();
  for (int k = threadIdx.x; k < SL; k += 256){
    const float* kp = key + ((size_t)b*SL + (k >> 6))*DM + h*DH + (k & 63);
    float acc = 0.f;
    #pragma unroll
    for (int d = 0; d < DH; ++d)
      acc = fmaf(qs[d], kp[(size_t)d*32*DM], acc);
    maskrows[((size_t)bh*NTOP + t)*SL + k] = acc;
  }
}

// ---------- flash attention, swapped-QK layout, KVBLK=128, zero LDS ----------
// S^T = mfma(K,Q): lane(lr,lg) reg j = S[q=q0+lr][k=k0+t*16+lg*4+j] -> softmax is
// lane-local + 2 shfls. P stays in registers as a valid MFMA operand under a
// k-permutation; V fragments are loaded with the matching permutation (2x8B).
// O accumulated transposed: acc[c] reg j = O[d=c*16+lg*4+j][q=q0+lr] -> alpha
// rescale and 1/lsum are lane-local; output stores are packed 8B.
__global__ __launch_bounds__(256) void flash_kernel(const s16* __restrict__ Qp, const s16* __restrict__ Kp,
        const s16* __restrict__ VpT, const float* __restrict__ maskrows, const int* __restrict__ rowsel,
        s16* __restrict__ outh){
  int bid = blockIdx.x;
  int qt = bid & 31, h = (bid >> 5) & 7, b = bid >> 8;
  int w = threadIdx.x >> 6, l = threadIdx.x & 63;
  int lr = l & 15, lg = l >> 4;
  int q0 = qt*64 + w*16;
  int bh = b*NH + h;
  const s16* qp = Qp + ((size_t)b*SL + q0 + lr)*DM + h*DH + lg*8;
  short8 bq0 = *(const short8*)qp;
  short8 bq1 = *(const short8*)(qp + 32);
  int sel = rowsel[(size_t)bh*SL + q0 + lr];
  const float* mrow = maskrows + ((size_t)bh*NTOP + (sel >= 0 ? sel : 0))*SL;
  const s16* kpb = Kp + (size_t)b*SL*DM + h*DH;
  const s16* vtb = VpT + (size_t)bh*DH*SL;
  f32x4 acc[4] = {};
  float m = -1e30f, lsum = 0.f;
  const float c1 = 0.125f * LOG2E;
  for (int k0 = 0; k0 < SL; k0 += 128){
    float sv[8][4];
    #pragma unroll
    for (int t = 0; t < 8; ++t){
      const s16* kp = kpb + (size_t)(k0 + t*16 + lr)*DM + lg*8;
      short8 ka0 = *(const short8*)kp;
      short8 ka1 = *(const short8*)(kp + 32);
      f32x4 s = {};
      s = mfma16(ka0, bq0, s);
      s = mfma16(ka1, bq1, s);
      #pragma unroll
      for (int j = 0; j < 4; ++j) sv[t][j] = s[j]*c1;
    }
    if (sel >= 0){
      #pragma unroll
      for (int t = 0; t < 8; ++t)
        #pragma unroll
        for (int j = 0; j < 4; ++j)
          sv[t][j] += mrow[k0 + t*16 + lg*4 + j]*LOG2E;
    }
    float mx = sv[0][0];
    #pragma unroll
    for (int t = 0; t < 8; ++t)
      #pragma unroll
      for (int j = 0; j < 4; ++j) mx = fmaxf(mx, sv[t][j]);
    mx = fmaxf(mx, __shfl_xor(mx, 16));
    mx = fmaxf(mx, __shfl_xor(mx, 32));
    float mnew = fmaxf(m, mx);
    float alpha = exp2f(m - mnew);
    m = mnew;
    float rs = 0.f;
    #pragma unroll
    for (int t = 0; t < 8; ++t)
      #pragma unroll
      for (int j = 0; j < 4; ++j){
        float p = exp2f(sv[t][j] - mnew);
        sv[t][j] = p;
        rs += p;
      }
    rs += __shfl_xor(rs, 16);
    rs += __shfl_xor(rs, 32);
    lsum = lsum*alpha + rs;
    #pragma unroll
    for (int c = 0; c < 4; ++c)
      #pragma unroll
      for (int j = 0; j < 4; ++j) acc[c][j] *= alpha;
    short8 paf[4];
    #pragma unroll
    for (int kt = 0; kt < 4; ++kt){
      union { unsigned u[4]; short8 s; } uu;
      uu.u[0] = cvtpk(sv[2*kt][0],   sv[2*kt][1]);
      uu.u[1] = cvtpk(sv[2*kt][2],   sv[2*kt][3]);
      uu.u[2] = cvtpk(sv[2*kt+1][0], sv[2*kt+1][1]);
      uu.u[3] = cvtpk(sv[2*kt+1][2], sv[2*kt+1][3]);
      paf[kt] = uu.s;
    }
    #pragma unroll
    for (int c = 0; c < 4; ++c){
      const s16* vp = vtb + (size_t)(c*16 + lr)*SL + k0 + lg*4;
      #pragma unroll
      for (int kt = 0; kt < 4; ++kt){
        short4_t lo = *(const short4_t*)(vp + kt*32);
        short4_t hi = *(const short4_t*)(vp + kt*32 + 16);
        short8 vf = __builtin_shufflevector(lo, hi, 0, 1, 2, 3, 4, 5, 6, 7);
        acc[c] = mfma16(vf, paf[kt], acc[c]);
      }
    }
  }
  float rinv = 1.0f / lsum;
  size_t orow = ((size_t)b*SL + q0 + lr)*DM + h*DH;
  #pragma unroll
  for (int c = 0; c < 4; ++c){
    uint2 val;
    val.x = cvtpk(acc[c][0]*rinv, acc[c][1]*rinv);
    val.y = cvtpk(acc[c][2]*rinv, acc[c][3]*rinv);
    *(uint2*)(outh + orow + c*16 + lg*4) = val;
  }
}

extern "C" void kernel_launch(void* const* d_in, const int* in_sizes, int n_in,
                              void* d_out, int out_size, void* d_ws, size_t ws_size,
                              hipStream_t stream){
  (void)in_sizes; (void)n_in; (void)out_size;
  const float* query = (const float*)d_in[0];
  const float* key   = (const float*)d_in[1];
  const float* value = (const float*)d_in[2];
  const float* wq    = (const float*)d_in[3];
  const float* wk    = (const float*)d_in[4];
  const float* wv    = (const float*)d_in[5];
  const float* bq    = (const float*)d_in[6];
  const float* bk    = (const float*)d_in[7];
  const float* bv    = (const float*)d_in[8];
  const float* wo    = (const float*)d_in[9];
  const float* bo    = (const float*)d_in[10];

  const size_t NE = (size_t)NB*SL*DM;     // 2,097,152
  const size_t WE = (size_t)DM*DM;        // 262,144

  char* p = (char*)d_ws;
  size_t off = 0;
  auto alloc = [&](size_t n)->char*{ char* r = p + off; off += (n + 255) & ~(size_t)255; return r; };
  s16* q_hi = (s16*)alloc(NE*2);
  s16* q_lo = (s16*)alloc(NE*2);
  s16* xk   = (s16*)alloc(NE*2);
  s16* xv   = (s16*)alloc(NE*2);
  s16* khatT_hi = (s16*)alloc(NE*2);
  s16* khatT_lo = (s16*)alloc(NE*2);
  s16* wqb = (s16*)alloc(WE*2);
  s16* wkb = (s16*)alloc(WE*2);
  s16* wvb = (s16*)alloc(WE*2);
  s16* wob = (s16*)alloc(WE*2);
  s16* Qp  = (s16*)alloc(NE*2);
  s16* Kp  = (s16*)alloc(NE*2);
  s16* Vp  = (s16*)alloc(NE*2);
  s16* VpT = (s16*)alloc(NE*2);
  float* M      = (float*)alloc((size_t)NB*NH*SL*4);
  int* topidx   = (int*)alloc((size_t)NB*NH*8*4);
  int* rowsel   = (int*)alloc((size_t)NB*NH*SL*4);
  float* maskrows = (float*)alloc((size_t)NB*NH*NTOP*SL*4);
  s16* outh = (s16*)alloc(NE*2);
  if (off > ws_size) return;  // insufficient scratch -> visible failure, no OOB writes

  const int nbb = (int)(NE/256);   // 8192
  const int wbb = (int)(WE/256);   // 1024
  prep_kernel<<<4*nbb + 4*wbb, 256, 0, stream>>>(query, key, value, wq, wk, wv, wo,
      q_hi, q_lo, xk, xv, khatT_hi, khatT_lo, wqb, wkb, wvb, wob);

  gemm_proj<<<3*512, 256, 0, stream>>>(q_hi, xk, xv, wqb, wkb, wvb, bq, bk, bv, Qp, Kp, Vp);
  vpt_kernel<<<nbb, 256, 0, stream>>>(Vp, VpT);

  stats_kernel<<<NB*NH*(SL/64), 256, 0, stream>>>(q_hi, q_lo, khatT_hi, khatT_lo, M);
  topk_kernel<<<NB*NH, 64, 0, stream>>>(M, topidx, rowsel);
  maskrow_kernel<<<NB*NH*NTOP, 256, 0, stream>>>(query, key, topidx, maskrows);

  flash_kernel<<<NB*NH*(SL/64), 256, 0, stream>>>(Qp, Kp, VpT, maskrows, rowsel, outh);
  gemm_out<<<512, 256, 0, stream>>>(outh, wob, bo, (float*)d_out);
}